// Round 1
// 103.705 us; speedup vs baseline: 1.0101x; 1.0101x over previous
//
#include <hip/hip_runtime.h>
#include <hip/hip_bf16.h>

// Problem constants (match reference)
constexpr int B  = 8;
constexpr int NQ = 256;
constexpr int NK = 512;
constexpr int D  = 256;   // DQ == DK == 256
constexpr int DV = 256;
constexpr int H  = 64;
constexpr float NEG = -1e6f;
constexpr float LOG2E = 1.4426950408889634f;
constexpr float CSCALE = 2.f * LOG2E;   // folded into projected q,k

// ---------------------------------------------------------------------------
// Kernel 1: project queries and keys, PRE-SCALED by 2*log2e.
//   out[r,h] = CSCALE * sum_d in[r,d] * W[d,h]
// RPB=32 rows per block, 512 threads (8 waves): thread (h = t&63, g = t>>6)
// computes rows g, g+8, g+16, g+24 -> 4 FMAs per W load (same W:FMA ratio as
// the old RPB=16 version) but 192 blocks = ONE dispatch round (no half-empty
// second round) and 2 waves/SIMD for latency hiding instead of 1.
// Row reads are wave-uniform LDS broadcasts (g is wave-uniform), conflict-free.
// ---------------------------------------------------------------------------
constexpr int RPB = 32;   // rows per block

__global__ __launch_bounds__(512) void proj_kernel(
    const float* __restrict__ queries, const float* __restrict__ keys,
    const float* __restrict__ Wq, const float* __restrict__ Wk,
    float* __restrict__ qp, float* __restrict__ kp)
{
    const int r0 = blockIdx.x * RPB;
    const bool isQ = (r0 < B * NQ);         // q-rows first (2048 = 64 blocks), then k-rows
    const float* src = isQ ? queries + (size_t)r0 * D
                           : keys + (size_t)(r0 - B * NQ) * D;
    const float* W   = isQ ? Wq : Wk;
    float* out       = isQ ? qp + (size_t)r0 * H
                           : kp + (size_t)(r0 - B * NQ) * H;

    __shared__ __align__(16) float rows[RPB][D];   // 32 KB
    // 32 rows * 64 float4 = 2048 float4; 512 threads -> 4 each (coalesced)
#pragma unroll
    for (int j = 0; j < 4; ++j)
        ((float4*)&rows[0][0])[threadIdx.x + j * 512] =
            ((const float4*)src)[threadIdx.x + j * 512];
    __syncthreads();

    const int h = threadIdx.x & 63;
    const int g = threadIdx.x >> 6;         // wave id 0..7; rows g, g+8, g+16, g+24
    float s0 = 0.f, s1 = 0.f, s2 = 0.f, s3 = 0.f;
#pragma unroll 2
    for (int d4 = 0; d4 < D / 4; ++d4) {
        float w0 = W[(d4 * 4 + 0) * H + h];
        float w1 = W[(d4 * 4 + 1) * H + h];
        float w2 = W[(d4 * 4 + 2) * H + h];
        float w3 = W[(d4 * 4 + 3) * H + h];
        float4 ra = *(const float4*)&rows[g][d4 * 4];
        float4 rb = *(const float4*)&rows[g + 8][d4 * 4];
        float4 rc = *(const float4*)&rows[g + 16][d4 * 4];
        float4 rd = *(const float4*)&rows[g + 24][d4 * 4];
        s0 = fmaf(ra.x, w0, s0);  s1 = fmaf(rb.x, w0, s1);
        s2 = fmaf(rc.x, w0, s2);  s3 = fmaf(rd.x, w0, s3);
        s0 = fmaf(ra.y, w1, s0);  s1 = fmaf(rb.y, w1, s1);
        s2 = fmaf(rc.y, w1, s2);  s3 = fmaf(rd.y, w1, s3);
        s0 = fmaf(ra.z, w2, s0);  s1 = fmaf(rb.z, w2, s1);
        s2 = fmaf(rc.z, w2, s2);  s3 = fmaf(rd.z, w2, s3);
        s0 = fmaf(ra.w, w3, s0);  s1 = fmaf(rb.w, w3, s1);
        s2 = fmaf(rc.w, w3, s2);  s3 = fmaf(rd.w, w3, s3);
    }
    out[g * H + h]         = s0 * CSCALE;
    out[(g + 8) * H + h]   = s1 * CSCALE;
    out[(g + 16) * H + h]  = s2 * CSCALE;
    out[(g + 24) * H + h]  = s3 * CSCALE;
}

// ---------------------------------------------------------------------------
// Kernel 2: scores + masked softmax + attn@V.
// Grid: 512 blocks, 512 threads = 8 waves.  b = blockIdx&7 so the 64 blocks
// of one batch land on one XCD (round-robin dispatch) -> V[b],K[b] stay in
// that XCD's 4 MiB L2.  Wave w: query (w>>1), key-half (w&1) for scores.
// Keys staged in LDS tiles of 128, stride 68 (b128 quarter-wave phase -> 2-way
// = conflict-free).  q,k pre-scaled so tanh elem = rcp(exp2(q+k)+1), no mul.
//
// Score inner loop uses a QUAD RATIONAL COMBINE: sum_i w_i/A_i over 4 elems
// is merged pairwise into one numerator/denominator -> 4 exp2 + ONE rcp per
// quad (was 4 rcp).  Trans pipe (quarter rate, the binding pipe) drops from
// 64 -> 40 cyc/quad; VALU rises 24 -> 36, LDS 36: pipes balanced.
// Exact algebra; one rcp approx error per quad instead of four.
//
// AV: 4-key chunks round-robined across all 8 waves (load-balanced in vlen),
// each chunk's V rows FMA'd into partials for ALL 4 queries; LDS reduce.
// ---------------------------------------------------------------------------
constexpr int KT   = 128;   // keys per LDS tile
constexpr int KPAD = 68;    // row stride (floats): 272 B, 16B-aligned

#define FMA4(acc, a, v) \
    acc.x = fmaf(a, v.x, acc.x); acc.y = fmaf(a, v.y, acc.y); \
    acc.z = fmaf(a, v.z, acc.z); acc.w = fmaf(a, v.w, acc.w);

__global__ __launch_bounds__(512, 4) void attn_kernel(
    const float* __restrict__ qp, const float* __restrict__ kp,
    const float* __restrict__ values, const int* __restrict__ valid_lens,
    const float* __restrict__ wv, float* __restrict__ out)
{
    const int b    = blockIdx.x & 7;         // batch <-> XCD
    const int q0   = (blockIdx.x >> 3) * 4;  // first query of this block
    const int t    = threadIdx.x;
    const int w    = t >> 6;                 // wave id (0..7)
    const int l    = t & 63;                 // lane
    const int qloc = w >> 1;                 // local query (0..3)
    const int half = w & 1;                  // key-half within tile

    __shared__ __align__(16) float kT[KT * KPAD];  // 34816 B; aliased as pt[8][4][256] in AV
    __shared__ __align__(16) float qv[4][H];
    __shared__ __align__(16) float w2[H];
    __shared__ __align__(16) float sc[4][NK];

    // per-query row into LDS (one of the wave pair)
    if (half == 0)
        qv[qloc][l] = qp[((size_t)b * NQ + q0 + qloc) * H + l];

    // wv: lane l holds wv[l]; butterfly-sum for sum_wv; w2 = -2*wv
    const float wvl = wv[l];
    float swv = wvl;
#pragma unroll
    for (int off = 32; off > 0; off >>= 1) swv += __shfl_xor(swv, off);
    if (w == 0) w2[l] = -2.f * wvl;

    const int vlen = valid_lens[b];

    // ---- score phase: 4 key tiles of 128; wave handles 64 keys/tile ----
    for (int kt = 0; kt < NK / KT; ++kt) {
        const int kg = kt * KT + half * 64 + l;   // this lane's global key
        if (kt * KT < vlen) {                     // block-uniform
            __syncthreads();   // protect previous tile's reads + first-iter qv/w2
            // stage 128 keys x 64 h = 2048 float4, 4 per thread, coalesced
            const float* src = kp + ((size_t)b * NK + kt * KT) * H;
#pragma unroll
            for (int j = 0; j < 4; ++j) {
                int idx4 = t + j * 512;
                int kk = idx4 >> 4;            // 16 float4 per 64-float row
                int hb = (idx4 & 15) * 4;
                float4 v = ((const float4*)src)[idx4];
                *(float4*)&kT[kk * KPAD + hb] = v;
            }
            __syncthreads();

            if (kt * KT + half * 64 < vlen) {     // wave-uniform: any live key?
                const float* qrow = &qv[qloc][0];
                const float* krow = &kT[(half * 64 + l) * KPAD];
                float s0 = 0.f;
#pragma unroll
                for (int h4 = 0; h4 < H / 4; ++h4) {
                    float4 qq = *(const float4*)&qrow[h4 * 4];
                    float4 ww = *(const float4*)&w2[h4 * 4];
                    float4 kk = *(const float4*)&krow[h4 * 4];
                    // A_i = exp2(q+k) + 1 ; want s0 += sum_i ww_i / A_i
                    float Ax = __builtin_amdgcn_exp2f(qq.x + kk.x) + 1.f;
                    float Ay = __builtin_amdgcn_exp2f(qq.y + kk.y) + 1.f;
                    float Az = __builtin_amdgcn_exp2f(qq.z + kk.z) + 1.f;
                    float Aw = __builtin_amdgcn_exp2f(qq.w + kk.w) + 1.f;
                    // pair combine: w_x/Ax + w_y/Ay = (w_x*Ay + w_y*Ax)/(Ax*Ay)
                    float n1 = fmaf(ww.x, Ay, ww.y * Ax);
                    float d1 = Ax * Ay;
                    float n2 = fmaf(ww.z, Aw, ww.w * Az);
                    float d2 = Az * Aw;
                    // quad combine: one rcp for 4 elements
                    float nq = fmaf(n1, d2, n2 * d1);
                    float dq = d1 * d2;        // >= 1, <= ~1e27: no over/underflow
                    s0 = fmaf(nq, __builtin_amdgcn_rcpf(dq), s0);
                }
                sc[qloc][kg] = (kg < vlen) ? (s0 + swv) : NEG;
            } else {
                sc[qloc][kg] = NEG;   // whole 64-key span masked: skip dot loop
            }
        } else {
            sc[qloc][kg] = NEG;   // fully masked tile
        }
    }
    __syncthreads();   // sc rows now complete (each written by 2 waves)

    // ---- softmax over sc[qloc][0..511] (both waves of pair compute identically) ----
    float vals[8];
    float m = -INFINITY;
#pragma unroll
    for (int j = 0; j < 8; ++j) {
        vals[j] = sc[qloc][l + j * 64];
        m = fmaxf(m, vals[j]);
    }
#pragma unroll
    for (int off = 32; off > 0; off >>= 1) m = fmaxf(m, __shfl_xor(m, off));
    float sum = 0.f;
#pragma unroll
    for (int j = 0; j < 8; ++j) {
        float p = __builtin_amdgcn_exp2f((vals[j] - m) * LOG2E);
        vals[j] = p;
        sum += p;
    }
#pragma unroll
    for (int off = 32; off > 0; off >>= 1) sum += __shfl_xor(sum, off);
    const float rinv = __builtin_amdgcn_rcpf(sum);
    // each wave of the pair writes its 4 of the 8 chunks (compile-time idx)
    if (half == 0) {
        sc[qloc][l + 0 * 64] = vals[0] * rinv;
        sc[qloc][l + 1 * 64] = vals[1] * rinv;
        sc[qloc][l + 2 * 64] = vals[2] * rinv;
        sc[qloc][l + 3 * 64] = vals[3] * rinv;
    } else {
        sc[qloc][l + 4 * 64] = vals[4] * rinv;
        sc[qloc][l + 5 * 64] = vals[5] * rinv;
        sc[qloc][l + 6 * 64] = vals[6] * rinv;
        sc[qloc][l + 7 * 64] = vals[7] * rinv;
    }
    __syncthreads();   // all normalized weights visible to all waves

    // ---- AV: 4-key chunks round-robined across the 8 waves (balanced) ----
    // attn[k] == 0 exactly for k >= vlen (exp2 underflow), so rounding the
    // chunk count up to a multiple of 4 keys is exact.
    float4 acc0 = {0,0,0,0}, acc1 = {0,0,0,0}, acc2 = {0,0,0,0}, acc3 = {0,0,0,0};
    const float* Vb = values + (size_t)b * NK * DV;
    const int nchunks = (vlen + 3) >> 2;
    for (int c = w; c < nchunks; c += 8) {
        const int k = 4 * c;
        float4 a0 = *(const float4*)&sc[0][k];
        float4 a1 = *(const float4*)&sc[1][k];
        float4 a2 = *(const float4*)&sc[2][k];
        float4 a3 = *(const float4*)&sc[3][k];
        const float* vr = Vb + (size_t)k * DV + 4 * l;
        float4 v0 = *(const float4*)(vr);
        float4 v1 = *(const float4*)(vr + DV);
        float4 v2 = *(const float4*)(vr + 2 * DV);
        float4 v3 = *(const float4*)(vr + 3 * DV);
        FMA4(acc0, a0.x, v0); FMA4(acc0, a0.y, v1); FMA4(acc0, a0.z, v2); FMA4(acc0, a0.w, v3);
        FMA4(acc1, a1.x, v0); FMA4(acc1, a1.y, v1); FMA4(acc1, a1.z, v2); FMA4(acc1, a1.w, v3);
        FMA4(acc2, a2.x, v0); FMA4(acc2, a2.y, v1); FMA4(acc2, a2.z, v2); FMA4(acc2, a2.w, v3);
        FMA4(acc3, a3.x, v0); FMA4(acc3, a3.y, v1); FMA4(acc3, a3.z, v2); FMA4(acc3, a3.w, v3);
    }

    // partials into LDS (alias over kT: 8 waves * 4 q * 256 v = 32 KB <= 34.8 KB)
    float* pt = kT;
    *(float4*)&pt[(w * 4 + 0) * 256 + 4 * l] = acc0;
    *(float4*)&pt[(w * 4 + 1) * 256 + 4 * l] = acc1;
    *(float4*)&pt[(w * 4 + 2) * 256 + 4 * l] = acc2;
    *(float4*)&pt[(w * 4 + 3) * 256 + 4 * l] = acc3;
    __syncthreads();

    // waves 0..3: final reduce + store for query w
    if (w < 4) {
        float4 r = {0,0,0,0};
#pragma unroll
        for (int s = 0; s < 8; ++s) {
            float4 p = *(const float4*)&pt[(s * 4 + w) * 256 + 4 * l];
            r.x += p.x; r.y += p.y; r.z += p.z; r.w += p.w;
        }
        *(float4*)&out[((size_t)b * NQ + q0 + w) * DV + 4 * l] = r;
    }
}

// ---------------------------------------------------------------------------
extern "C" void kernel_launch(void* const* d_in, const int* in_sizes, int n_in,
                              void* d_out, int out_size, void* d_ws, size_t ws_size,
                              hipStream_t stream) {
    const float* queries    = (const float*)d_in[0];
    const float* keys       = (const float*)d_in[1];
    const float* values     = (const float*)d_in[2];
    const int*   valid_lens = (const int*)d_in[3];
    const float* Wq         = (const float*)d_in[4];
    const float* Wk         = (const float*)d_in[5];
    const float* wv         = (const float*)d_in[6];
    float* out = (float*)d_out;

    float* qp = (float*)d_ws;                   // [B, NQ, H]  (pre-scaled by 2*log2e)
    float* kp = qp + (size_t)B * NQ * H;        // [B, NK, H]  (pre-scaled by 2*log2e)

    // projections: (2048 + 4096) rows / 32 per block, one dispatch round
    proj_kernel<<<(B * NQ + B * NK) / RPB, 512, 0, stream>>>(
        queries, keys, Wq, Wk, qp, kp);

    // attention: one block per (batch, 4-query tile); batch = blockIdx&7 (XCD-local)
    attn_kernel<<<B * (NQ / 4), 512, 0, stream>>>(
        qp, kp, values, valid_lens, wv, out);
}

// Round 2
// 103.248 us; speedup vs baseline: 1.0146x; 1.0044x over previous
//
#include <hip/hip_runtime.h>
#include <hip/hip_bf16.h>

// Problem constants (match reference)
constexpr int B  = 8;
constexpr int NQ = 256;
constexpr int NK = 512;
constexpr int D  = 256;   // DQ == DK == 256
constexpr int DV = 256;
constexpr int H  = 64;
constexpr float LOG2E = 1.4426950408889634f;
constexpr float CSCALE = 2.f * LOG2E;   // folded into projected q,k

// ---------------------------------------------------------------------------
// Kernel 1: project queries and keys, PRE-SCALED by 2*log2e.
//   out[r,h] = CSCALE * sum_d in[r,d] * W[d,h]
// RPB=32 rows per block, 512 threads (8 waves): thread (h = t&63, g = t>>6)
// computes rows g, g+8, g+16, g+24 -> 4 FMAs per W load; 192 blocks = one
// dispatch round, 2 waves/SIMD.  Row reads are wave-uniform LDS broadcasts.
// ---------------------------------------------------------------------------
constexpr int RPB = 32;   // rows per block

__global__ __launch_bounds__(512) void proj_kernel(
    const float* __restrict__ queries, const float* __restrict__ keys,
    const float* __restrict__ Wq, const float* __restrict__ Wk,
    float* __restrict__ qp, float* __restrict__ kp)
{
    const int r0 = blockIdx.x * RPB;
    const bool isQ = (r0 < B * NQ);         // q-rows first (2048 = 64 blocks), then k-rows
    const float* src = isQ ? queries + (size_t)r0 * D
                           : keys + (size_t)(r0 - B * NQ) * D;
    const float* W   = isQ ? Wq : Wk;
    float* out       = isQ ? qp + (size_t)r0 * H
                           : kp + (size_t)(r0 - B * NQ) * H;

    __shared__ __align__(16) float rows[RPB][D];   // 32 KB
#pragma unroll
    for (int j = 0; j < 4; ++j)
        ((float4*)&rows[0][0])[threadIdx.x + j * 512] =
            ((const float4*)src)[threadIdx.x + j * 512];
    __syncthreads();

    const int h = threadIdx.x & 63;
    const int g = threadIdx.x >> 6;         // wave id 0..7; rows g, g+8, g+16, g+24
    float s0 = 0.f, s1 = 0.f, s2 = 0.f, s3 = 0.f;
#pragma unroll 2
    for (int d4 = 0; d4 < D / 4; ++d4) {
        float w0 = W[(d4 * 4 + 0) * H + h];
        float w1 = W[(d4 * 4 + 1) * H + h];
        float w2 = W[(d4 * 4 + 2) * H + h];
        float w3 = W[(d4 * 4 + 3) * H + h];
        float4 ra = *(const float4*)&rows[g][d4 * 4];
        float4 rb = *(const float4*)&rows[g + 8][d4 * 4];
        float4 rc = *(const float4*)&rows[g + 16][d4 * 4];
        float4 rd = *(const float4*)&rows[g + 24][d4 * 4];
        s0 = fmaf(ra.x, w0, s0);  s1 = fmaf(rb.x, w0, s1);
        s2 = fmaf(rc.x, w0, s2);  s3 = fmaf(rd.x, w0, s3);
        s0 = fmaf(ra.y, w1, s0);  s1 = fmaf(rb.y, w1, s1);
        s2 = fmaf(rc.y, w1, s2);  s3 = fmaf(rd.y, w1, s3);
        s0 = fmaf(ra.z, w2, s0);  s1 = fmaf(rb.z, w2, s1);
        s2 = fmaf(rc.z, w2, s2);  s3 = fmaf(rd.z, w2, s3);
        s0 = fmaf(ra.w, w3, s0);  s1 = fmaf(rb.w, w3, s1);
        s2 = fmaf(rc.w, w3, s2);  s3 = fmaf(rd.w, w3, s3);
    }
    out[g * H + h]         = s0 * CSCALE;
    out[(g + 8) * H + h]   = s1 * CSCALE;
    out[(g + 16) * H + h]  = s2 * CSCALE;
    out[(g + 24) * H + h]  = s3 * CSCALE;
}

// ---------------------------------------------------------------------------
// Kernel 2: scores + masked softmax + attn@V, 8 QUERIES PER BLOCK.
// Grid: 256 blocks x 1024 threads (16 waves) = exactly 1 block/CU, 4 waves/
// SIMD.  b = blockIdx&7 -> all 32 blocks of a batch land on one XCD (V,K
// L2-resident).  Amortization: each block's staged K tiles and loaded V rows
// now serve 8 queries (was 4) -> V L2 traffic and K staging traffic HALVED.
//
// Score: wave w handles query (w>>1), key-half (w&1) of each 128-key tile.
// Tile kt+1 is prefetched into registers while tile kt computes (T14 split) —
// with 1 block/CU there is no second block to hide staging latency.
// Scores are bounded (|s| <= ~7) so NO max-subtraction is needed: sc holds
// e^score directly (masked keys -> exactly 0).  Softmax reduces to a row-sum;
// normalization (1/sum) is folded into the final output reduce.
//
// AV: wave-pair p = w>>1 owns chunks c = p, p+8, ...; the two waves of a pair
// split the 256-wide V row (float2 per lane, half*128 offset).  Each V row is
// read ONCE per block from L2.  Partials: 8 pairs x 8 q x 256 v = 64 KB ->
// reduced in 2 passes over the 32 KB kT alias, 4 waves per pass.
// ---------------------------------------------------------------------------
constexpr int KT   = 128;   // keys per LDS tile
constexpr int KPAD = 68;    // row stride (floats): 272 B, 16B-aligned, 2-way banks
constexpr int QPB  = 8;     // queries per block

#define FMA2(acc, a, v) \
    acc.x = fmaf(a, v.x, acc.x); acc.y = fmaf(a, v.y, acc.y);
#define AVQ(acc, aq) \
    FMA2(acc, aq.x, v0) FMA2(acc, aq.y, v1) FMA2(acc, aq.z, v2) FMA2(acc, aq.w, v3)

__global__ __launch_bounds__(1024, 4) void attn_kernel(
    const float* __restrict__ qp, const float* __restrict__ kp,
    const float* __restrict__ values, const int* __restrict__ valid_lens,
    const float* __restrict__ wv, float* __restrict__ out)
{
    const int b    = blockIdx.x & 7;         // batch <-> XCD
    const int q0   = (blockIdx.x >> 3) * QPB;
    const int t    = threadIdx.x;
    const int w    = t >> 6;                 // wave id (0..15)
    const int l    = t & 63;                 // lane
    const int qloc = w >> 1;                 // local query / AV pair id (0..7)
    const int half = w & 1;                  // key-half (score) / v-half (AV)

    __shared__ __align__(16) float kT[KT * KPAD];  // 34816 B; aliased as pt[32][256] in reduce
    __shared__ __align__(16) float qv[QPB][H];
    __shared__ __align__(16) float w2[H];
    __shared__ __align__(16) float rq[QPB];
    __shared__ __align__(16) float sc[QPB][NK];    // e^score (0 where masked)

    // per-query row into LDS (one wave of each pair)
    if (half == 0)
        qv[qloc][l] = qp[((size_t)b * NQ + q0 + qloc) * H + l];

    // wv: lane l holds wv[l]; butterfly-sum for sum_wv; w2 = -2*wv
    const float wvl = wv[l];
    float swv = wvl;
#pragma unroll
    for (int off = 32; off > 0; off >>= 1) swv += __shfl_xor(swv, off);
    if (w == 0) w2[l] = -2.f * wvl;

    const int vlen = valid_lens[b];
    const int ntl  = (vlen + KT - 1) / KT;   // live tiles (1..4)

    // zero the fully-dead sc region (e^score == 0 for masked keys)
    for (int kt = ntl; kt < NK / KT; ++kt)
        sc[qloc][kt * KT + half * 64 + l] = 0.f;

    // ---- score phase with register prefetch of the next K tile ----
    const float* kb = kp + (size_t)b * NK * H;
    float4 r0 = ((const float4*)kb)[t];          // tile 0 (always live)
    float4 r1 = ((const float4*)kb)[t + 1024];

    for (int kt = 0; kt < ntl; ++kt) {
        __syncthreads();   // prev tile's kT reads done; also covers qv/w2 on kt=0
        {   // 2048 float4 staged by 1024 threads (2 each) from regs
            int i4 = t;
            *(float4*)&kT[(i4 >> 4) * KPAD + (i4 & 15) * 4] = r0;
            i4 = t + 1024;
            *(float4*)&kT[(i4 >> 4) * KPAD + (i4 & 15) * 4] = r1;
        }
        if (kt + 1 < ntl) {   // prefetch next tile; latency hides under compute
            const float* nsrc = kb + (size_t)(kt + 1) * KT * H;
            r0 = ((const float4*)nsrc)[t];
            r1 = ((const float4*)nsrc)[t + 1024];
        }
        __syncthreads();

        const int kg = kt * KT + half * 64 + l;   // this lane's global key
        if (kt * KT + half * 64 < vlen) {         // wave-uniform: any live key?
            const float* qrow = &qv[qloc][0];
            const float* krow = &kT[(half * 64 + l) * KPAD];
            float s0 = 0.f;
#pragma unroll
            for (int h4 = 0; h4 < H / 4; ++h4) {
                float4 qq = *(const float4*)&qrow[h4 * 4];
                float4 ww = *(const float4*)&w2[h4 * 4];
                float4 kk = *(const float4*)&krow[h4 * 4];
                // A_i = exp2(q+k) + 1 ; s0 += sum_i ww_i / A_i  (quad rational)
                float Ax = __builtin_amdgcn_exp2f(qq.x + kk.x) + 1.f;
                float Ay = __builtin_amdgcn_exp2f(qq.y + kk.y) + 1.f;
                float Az = __builtin_amdgcn_exp2f(qq.z + kk.z) + 1.f;
                float Aw = __builtin_amdgcn_exp2f(qq.w + kk.w) + 1.f;
                float n1 = fmaf(ww.x, Ay, ww.y * Ax);
                float d1 = Ax * Ay;
                float n2 = fmaf(ww.z, Aw, ww.w * Az);
                float d2 = Az * Aw;
                float nq = fmaf(n1, d2, n2 * d1);
                float dq = d1 * d2;
                s0 = fmaf(nq, __builtin_amdgcn_rcpf(dq), s0);
            }
            // store e^score directly (no max needed: |score| <= ~7)
            sc[qloc][kg] = (kg < vlen)
                ? __builtin_amdgcn_exp2f((s0 + swv) * LOG2E) : 0.f;
        } else {
            sc[qloc][kg] = 0.f;   // whole 64-key span masked
        }
    }
    __syncthreads();   // sc rows complete

    // ---- row sums (pair-redundant), 1/sum into rq ----
    float sum = 0.f;
#pragma unroll
    for (int j = 0; j < 8; ++j) sum += sc[qloc][l + j * 64];
#pragma unroll
    for (int off = 32; off > 0; off >>= 1) sum += __shfl_xor(sum, off);
    if (half == 0 && l == 0) rq[qloc] = __builtin_amdgcn_rcpf(sum);

    // ---- AV: pair p = qloc owns chunks p, p+8, ...; waves split V width ----
    // sc[q][k] == 0 exactly for k >= vlen, so 4-key chunk rounding is exact.
    float2 acc0{0,0}, acc1{0,0}, acc2{0,0}, acc3{0,0};
    float2 acc4{0,0}, acc5{0,0}, acc6{0,0}, acc7{0,0};
    const float* Vb = values + (size_t)b * NK * DV + half * 128 + 2 * l;
    const int nchunks = (vlen + 3) >> 2;
    for (int c = qloc; c < nchunks; c += 8) {
        const int k = 4 * c;
        float4 a0 = *(const float4*)&sc[0][k];   // uniform addr -> LDS broadcast
        float4 a1 = *(const float4*)&sc[1][k];
        float4 a2 = *(const float4*)&sc[2][k];
        float4 a3 = *(const float4*)&sc[3][k];
        float4 a4 = *(const float4*)&sc[4][k];
        float4 a5 = *(const float4*)&sc[5][k];
        float4 a6 = *(const float4*)&sc[6][k];
        float4 a7 = *(const float4*)&sc[7][k];
        const float* vr = Vb + (size_t)k * DV;
        float2 v0 = *(const float2*)(vr);
        float2 v1 = *(const float2*)(vr + DV);
        float2 v2 = *(const float2*)(vr + 2 * DV);
        float2 v3 = *(const float2*)(vr + 3 * DV);
        AVQ(acc0, a0) AVQ(acc1, a1) AVQ(acc2, a2) AVQ(acc3, a3)
        AVQ(acc4, a4) AVQ(acc5, a5) AVQ(acc6, a6) AVQ(acc7, a7)
    }

    // ---- reduce: 2 passes of 4 queries over the 32 KB kT alias ----
    float* pt = kT;   // pt[(pair*4 + qq)*256 + v]
    const int pbase = qloc * 4 * 256 + half * 128 + 2 * l;
    *(float2*)&pt[pbase + 0 * 256] = acc0;
    *(float2*)&pt[pbase + 1 * 256] = acc1;
    *(float2*)&pt[pbase + 2 * 256] = acc2;
    *(float2*)&pt[pbase + 3 * 256] = acc3;
    __syncthreads();
    if (w < 4) {   // wave w reduces query w
        float4 r{0,0,0,0};
#pragma unroll
        for (int p = 0; p < 8; ++p) {
            float4 x = *(const float4*)&pt[(p * 4 + w) * 256 + 4 * l];
            r.x += x.x; r.y += x.y; r.z += x.z; r.w += x.w;
        }
        const float s = rq[w];
        r.x *= s; r.y *= s; r.z *= s; r.w *= s;
        *(float4*)&out[((size_t)b * NQ + q0 + w) * DV + 4 * l] = r;
    }
    __syncthreads();
    *(float2*)&pt[pbase + 0 * 256] = acc4;
    *(float2*)&pt[pbase + 1 * 256] = acc5;
    *(float2*)&pt[pbase + 2 * 256] = acc6;
    *(float2*)&pt[pbase + 3 * 256] = acc7;
    __syncthreads();
    if (w < 4) {   // wave w reduces query 4+w
        float4 r{0,0,0,0};
#pragma unroll
        for (int p = 0; p < 8; ++p) {
            float4 x = *(const float4*)&pt[(p * 4 + w) * 256 + 4 * l];
            r.x += x.x; r.y += x.y; r.z += x.z; r.w += x.w;
        }
        const float s = rq[4 + w];
        r.x *= s; r.y *= s; r.z *= s; r.w *= s;
        *(float4*)&out[((size_t)b * NQ + q0 + 4 + w) * DV + 4 * l] = r;
    }
}

// ---------------------------------------------------------------------------
extern "C" void kernel_launch(void* const* d_in, const int* in_sizes, int n_in,
                              void* d_out, int out_size, void* d_ws, size_t ws_size,
                              hipStream_t stream) {
    const float* queries    = (const float*)d_in[0];
    const float* keys       = (const float*)d_in[1];
    const float* values     = (const float*)d_in[2];
    const int*   valid_lens = (const int*)d_in[3];
    const float* Wq         = (const float*)d_in[4];
    const float* Wk         = (const float*)d_in[5];
    const float* wv         = (const float*)d_in[6];
    float* out = (float*)d_out;

    float* qp = (float*)d_ws;                   // [B, NQ, H]  (pre-scaled by 2*log2e)
    float* kp = qp + (size_t)B * NQ * H;        // [B, NK, H]  (pre-scaled by 2*log2e)

    // projections: (2048 + 4096) rows / 32 per block, one dispatch round
    proj_kernel<<<(B * NQ + B * NK) / RPB, 512, 0, stream>>>(
        queries, keys, Wq, Wk, qp, kp);

    // attention: one block per (batch, 8-query tile); batch = blockIdx&7 (XCD-local)
    attn_kernel<<<B * (NQ / QPB), 1024, 0, stream>>>(
        qp, kp, values, valid_lens, wv, out);
}

// Round 3
// 103.002 us; speedup vs baseline: 1.0170x; 1.0024x over previous
//
#include <hip/hip_runtime.h>
#include <hip/hip_bf16.h>

// Problem constants (match reference)
constexpr int B  = 8;
constexpr int NQ = 256;
constexpr int NK = 512;
constexpr int D  = 256;   // DQ == DK == 256
constexpr int DV = 256;
constexpr int H  = 64;
constexpr float LOG2E = 1.4426950408889634f;
constexpr float CSCALE = 2.f * LOG2E;   // folded into projected q,k

// ---------------------------------------------------------------------------
// Kernel 1: project queries and keys, PRE-SCALED by 2*log2e.
//   out[r,h] = CSCALE * sum_d in[r,d] * W[d,h]
// RPB=32 rows per block, 512 threads (8 waves): thread (h = t&63, g = t>>6)
// computes rows g, g+8, g+16, g+24 -> 4 FMAs per W load; 192 blocks = one
// dispatch round, 2 waves/SIMD.  unroll 4 -> 16 W loads in flight per wave
// (proj is L2-latency-exposed at this occupancy; deeper pipeline hides it).
// ---------------------------------------------------------------------------
constexpr int RPB = 32;   // rows per block

__global__ __launch_bounds__(512) void proj_kernel(
    const float* __restrict__ queries, const float* __restrict__ keys,
    const float* __restrict__ Wq, const float* __restrict__ Wk,
    float* __restrict__ qp, float* __restrict__ kp)
{
    const int r0 = blockIdx.x * RPB;
    const bool isQ = (r0 < B * NQ);         // q-rows first (2048 = 64 blocks), then k-rows
    const float* src = isQ ? queries + (size_t)r0 * D
                           : keys + (size_t)(r0 - B * NQ) * D;
    const float* W   = isQ ? Wq : Wk;
    float* out       = isQ ? qp + (size_t)r0 * H
                           : kp + (size_t)(r0 - B * NQ) * H;

    __shared__ __align__(16) float rows[RPB][D];   // 32 KB
#pragma unroll
    for (int j = 0; j < 4; ++j)
        ((float4*)&rows[0][0])[threadIdx.x + j * 512] =
            ((const float4*)src)[threadIdx.x + j * 512];
    __syncthreads();

    const int h = threadIdx.x & 63;
    const int g = threadIdx.x >> 6;         // wave id 0..7; rows g, g+8, g+16, g+24
    float s0 = 0.f, s1 = 0.f, s2 = 0.f, s3 = 0.f;
#pragma unroll 4
    for (int d4 = 0; d4 < D / 4; ++d4) {
        float w0 = W[(d4 * 4 + 0) * H + h];
        float w1 = W[(d4 * 4 + 1) * H + h];
        float w2 = W[(d4 * 4 + 2) * H + h];
        float w3 = W[(d4 * 4 + 3) * H + h];
        float4 ra = *(const float4*)&rows[g][d4 * 4];
        float4 rb = *(const float4*)&rows[g + 8][d4 * 4];
        float4 rc = *(const float4*)&rows[g + 16][d4 * 4];
        float4 rd = *(const float4*)&rows[g + 24][d4 * 4];
        s0 = fmaf(ra.x, w0, s0);  s1 = fmaf(rb.x, w0, s1);
        s2 = fmaf(rc.x, w0, s2);  s3 = fmaf(rd.x, w0, s3);
        s0 = fmaf(ra.y, w1, s0);  s1 = fmaf(rb.y, w1, s1);
        s2 = fmaf(rc.y, w1, s2);  s3 = fmaf(rd.y, w1, s3);
        s0 = fmaf(ra.z, w2, s0);  s1 = fmaf(rb.z, w2, s1);
        s2 = fmaf(rc.z, w2, s2);  s3 = fmaf(rd.z, w2, s3);
        s0 = fmaf(ra.w, w3, s0);  s1 = fmaf(rb.w, w3, s1);
        s2 = fmaf(rc.w, w3, s2);  s3 = fmaf(rd.w, w3, s3);
    }
    out[g * H + h]         = s0 * CSCALE;
    out[(g + 8) * H + h]   = s1 * CSCALE;
    out[(g + 16) * H + h]  = s2 * CSCALE;
    out[(g + 24) * H + h]  = s3 * CSCALE;
}

// ---------------------------------------------------------------------------
// Kernel 2: scores + softmax + attn@V, 8 queries/block, PIPELINED PHASES.
// Grid: 256 blocks x 1024 threads (16 waves) = 1 block/CU, 4 waves/SIMD.
// b = blockIdx&7 -> batch pinned to one XCD (K,V L2-resident).
//
// Key change vs previous: the per-tile window that computes scores(kt) ALSO
// executes AV(kt-1).  sc[kt-1] is two barriers old (visible); AV never reads
// kT, so single-buffered staging is untouched and the barrier count per tile
// is UNCHANGED (2).  Effect: the trans-heavy score work and the pure-VALU AV
// work co-issue on different pipes via wave drift (score ~8192 trans-cyc +
// 6144 VALU-cyc; AV ~8192 VALU-cyc per tile -> mixed window is VALU-bound at
// ~3584 device-cyc/tile vs ~4480 phase-locked).  Score inner loop reverted to
// per-element rcp (3 VALU + 2 trans per elem) — cheaper on the binding VALU
// pipe than the quad-rational form (19 VALU + 5 trans per 4 elems).
//
// Scores are bounded (|s| <= ~7): sc holds e^score directly (masked -> 0);
// softmax = row-sum; 1/sum folded into the output reduce.
// ---------------------------------------------------------------------------
constexpr int KT   = 128;   // keys per LDS tile
constexpr int KPAD = 68;    // row stride (floats): 272 B, 16B-aligned, 2-way banks
constexpr int QPB  = 8;     // queries per block

#define FMA2(acc, a, v) \
    acc.x = fmaf(a, v.x, acc.x); acc.y = fmaf(a, v.y, acc.y);
#define AVQ(acc, aq) \
    FMA2(acc, aq.x, v0) FMA2(acc, aq.y, v1) FMA2(acc, aq.z, v2) FMA2(acc, aq.w, v3)

__global__ __launch_bounds__(1024, 4) void attn_kernel(
    const float* __restrict__ qp, const float* __restrict__ kp,
    const float* __restrict__ values, const int* __restrict__ valid_lens,
    const float* __restrict__ wv, float* __restrict__ out)
{
    const int b    = blockIdx.x & 7;         // batch <-> XCD
    const int q0   = (blockIdx.x >> 3) * QPB;
    const int t    = threadIdx.x;
    const int w    = t >> 6;                 // wave id (0..15)
    const int l    = t & 63;                 // lane
    const int qloc = w >> 1;                 // local query / AV pair id (0..7)
    const int half = w & 1;                  // key-half (score) / v-half (AV)

    __shared__ __align__(16) float kT[KT * KPAD];  // 34816 B; aliased as pt[32][256] in reduce
    __shared__ __align__(16) float qv[QPB][H];
    __shared__ __align__(16) float w2[H];
    __shared__ __align__(16) float rq[QPB];
    __shared__ __align__(16) float sc[QPB][NK];    // e^score (0 where masked)

    // per-query row into LDS (one wave of each pair)
    if (half == 0)
        qv[qloc][l] = qp[((size_t)b * NQ + q0 + qloc) * H + l];

    // wv: lane l holds wv[l]; butterfly-sum for sum_wv; w2 = -2*wv
    const float wvl = wv[l];
    float swv = wvl;
#pragma unroll
    for (int off = 32; off > 0; off >>= 1) swv += __shfl_xor(swv, off);
    if (w == 0) w2[l] = -2.f * wvl;

    const int vlen = valid_lens[b];
    const int ntl  = (vlen + KT - 1) / KT;   // live tiles (1..4)

    // zero the fully-dead sc region (e^score == 0 for masked keys)
    for (int kt = ntl; kt < NK / KT; ++kt)
        sc[qloc][kt * KT + half * 64 + l] = 0.f;

    // AV state: pair qloc owns 4 chunks per tile (qloc, qloc+8, +16, +24);
    // the two waves of a pair split the 256-wide V row (float2 per lane).
    float2 acc0{0,0}, acc1{0,0}, acc2{0,0}, acc3{0,0};
    float2 acc4{0,0}, acc5{0,0}, acc6{0,0}, acc7{0,0};
    const float* Vb = values + (size_t)b * NK * DV + half * 128 + 2 * l;

    auto av_tile = [&](int kt) {
#pragma unroll
        for (int cc = 0; cc < 4; ++cc) {
            const int k = kt * KT + 4 * (qloc + 8 * cc);
            if (k >= vlen) continue;              // wave-uniform skip (zeros)
            float4 a0 = *(const float4*)&sc[0][k];   // uniform addr -> broadcast
            float4 a1 = *(const float4*)&sc[1][k];
            float4 a2 = *(const float4*)&sc[2][k];
            float4 a3 = *(const float4*)&sc[3][k];
            float4 a4 = *(const float4*)&sc[4][k];
            float4 a5 = *(const float4*)&sc[5][k];
            float4 a6 = *(const float4*)&sc[6][k];
            float4 a7 = *(const float4*)&sc[7][k];
            const float* vr = Vb + (size_t)k * DV;
            float2 v0 = *(const float2*)(vr);
            float2 v1 = *(const float2*)(vr + DV);
            float2 v2 = *(const float2*)(vr + 2 * DV);
            float2 v3 = *(const float2*)(vr + 3 * DV);
            AVQ(acc0, a0) AVQ(acc1, a1) AVQ(acc2, a2) AVQ(acc3, a3)
            AVQ(acc4, a4) AVQ(acc5, a5) AVQ(acc6, a6) AVQ(acc7, a7)
        }
    };

    // ---- pipelined score/AV loop; 2 barriers per tile ----
    const float* kb = kp + (size_t)b * NK * H;
    float4 r0 = ((const float4*)kb)[t];          // tile 0 (always live)
    float4 r1 = ((const float4*)kb)[t + 1024];

    for (int kt = 0; kt < ntl; ++kt) {
        if (kt) __syncthreads();   // prev window's kT reads done; sc[kt-1] visible
        {   // 2048 float4 staged by 1024 threads (2 each) from regs
            int i4 = t;
            *(float4*)&kT[(i4 >> 4) * KPAD + (i4 & 15) * 4] = r0;
            i4 = t + 1024;
            *(float4*)&kT[(i4 >> 4) * KPAD + (i4 & 15) * 4] = r1;
        }
        if (kt + 1 < ntl) {   // prefetch next tile; latency hides under window
            const float* nsrc = kb + (size_t)(kt + 1) * KT * H;
            r0 = ((const float4*)nsrc)[t];
            r1 = ((const float4*)nsrc)[t + 1024];
        }
        __syncthreads();

        // -- window: scores(kt) [trans-heavy] + AV(kt-1) [VALU-heavy] --
        const int kg = kt * KT + half * 64 + l;   // this lane's global key
        if (kt * KT + half * 64 < vlen) {         // wave-uniform: any live key?
            const float* qrow = &qv[qloc][0];
            const float* krow = &kT[(half * 64 + l) * KPAD];
            float s0 = 0.f;
#pragma unroll
            for (int h4 = 0; h4 < H / 4; ++h4) {
                float4 qq = *(const float4*)&qrow[h4 * 4];
                float4 ww = *(const float4*)&w2[h4 * 4];
                float4 kk = *(const float4*)&krow[h4 * 4];
                // elem: r = 1/(2^(q+k) + 1); s0 += w2 * r  (3 VALU + 2 trans)
                float r;
                r = __builtin_amdgcn_rcpf(__builtin_amdgcn_exp2f(qq.x + kk.x) + 1.f);
                s0 = fmaf(ww.x, r, s0);
                r = __builtin_amdgcn_rcpf(__builtin_amdgcn_exp2f(qq.y + kk.y) + 1.f);
                s0 = fmaf(ww.y, r, s0);
                r = __builtin_amdgcn_rcpf(__builtin_amdgcn_exp2f(qq.z + kk.z) + 1.f);
                s0 = fmaf(ww.z, r, s0);
                r = __builtin_amdgcn_rcpf(__builtin_amdgcn_exp2f(qq.w + kk.w) + 1.f);
                s0 = fmaf(ww.w, r, s0);
            }
            // store e^score directly (no max needed: |score| <= ~7)
            sc[qloc][kg] = (kg < vlen)
                ? __builtin_amdgcn_exp2f((s0 + swv) * LOG2E) : 0.f;
        } else {
            sc[qloc][kg] = 0.f;   // whole 64-key span masked
        }

        if (kt > 0) av_tile(kt - 1);
    }
    __syncthreads();   // sc rows complete

    // ---- tail window: AV(last tile) + row sums ----
    av_tile(ntl - 1);
    float sum = 0.f;
#pragma unroll
    for (int j = 0; j < 8; ++j) sum += sc[qloc][l + j * 64];
#pragma unroll
    for (int off = 32; off > 0; off >>= 1) sum += __shfl_xor(sum, off);
    if (half == 0 && l == 0) rq[qloc] = __builtin_amdgcn_rcpf(sum);
    __syncthreads();   // kT free for reuse; rq visible

    // ---- reduce: 2 passes of 4 queries over the 32 KB kT alias ----
    float* pt = kT;   // pt[(pair*4 + qq)*256 + v]
    const int pbase = qloc * 4 * 256 + half * 128 + 2 * l;
    *(float2*)&pt[pbase + 0 * 256] = acc0;
    *(float2*)&pt[pbase + 1 * 256] = acc1;
    *(float2*)&pt[pbase + 2 * 256] = acc2;
    *(float2*)&pt[pbase + 3 * 256] = acc3;
    __syncthreads();
    if (w < 4) {   // wave w reduces query w
        float4 r{0,0,0,0};
#pragma unroll
        for (int p = 0; p < 8; ++p) {
            float4 x = *(const float4*)&pt[(p * 4 + w) * 256 + 4 * l];
            r.x += x.x; r.y += x.y; r.z += x.z; r.w += x.w;
        }
        const float s = rq[w];
        r.x *= s; r.y *= s; r.z *= s; r.w *= s;
        *(float4*)&out[((size_t)b * NQ + q0 + w) * DV + 4 * l] = r;
    }
    __syncthreads();
    *(float2*)&pt[pbase + 0 * 256] = acc4;
    *(float2*)&pt[pbase + 1 * 256] = acc5;
    *(float2*)&pt[pbase + 2 * 256] = acc6;
    *(float2*)&pt[pbase + 3 * 256] = acc7;
    __syncthreads();
    if (w < 4) {   // wave w reduces query 4+w
        float4 r{0,0,0,0};
#pragma unroll
        for (int p = 0; p < 8; ++p) {
            float4 x = *(const float4*)&pt[(p * 4 + w) * 256 + 4 * l];
            r.x += x.x; r.y += x.y; r.z += x.z; r.w += x.w;
        }
        const float s = rq[4 + w];
        r.x *= s; r.y *= s; r.z *= s; r.w *= s;
        *(float4*)&out[((size_t)b * NQ + q0 + 4 + w) * DV + 4 * l] = r;
    }
}

// ---------------------------------------------------------------------------
extern "C" void kernel_launch(void* const* d_in, const int* in_sizes, int n_in,
                              void* d_out, int out_size, void* d_ws, size_t ws_size,
                              hipStream_t stream) {
    const float* queries    = (const float*)d_in[0];
    const float* keys       = (const float*)d_in[1];
    const float* values     = (const float*)d_in[2];
    const int*   valid_lens = (const int*)d_in[3];
    const float* Wq         = (const float*)d_in[4];
    const float* Wk         = (const float*)d_in[5];
    const float* wv         = (const float*)d_in[6];
    float* out = (float*)d_out;

    float* qp = (float*)d_ws;                   // [B, NQ, H]  (pre-scaled by 2*log2e)
    float* kp = qp + (size_t)B * NQ * H;        // [B, NK, H]  (pre-scaled by 2*log2e)

    // projections: (2048 + 4096) rows / 32 per block, one dispatch round
    proj_kernel<<<(B * NQ + B * NK) / RPB, 512, 0, stream>>>(
        queries, keys, Wq, Wk, qp, kp);

    // attention: one block per (batch, 8-query tile); batch = blockIdx&7 (XCD-local)
    attn_kernel<<<B * (NQ / QPB), 1024, 0, stream>>>(
        qp, kp, values, valid_lens, wv, out);
}